// Round 1
// baseline (348.700 us; speedup 1.0000x reference)
//
#include <hip/hip_runtime.h>
#include <hip/hip_bf16.h>
#include <stdint.h>

#define NB 8192
#define ND 1024
#define NC 14

// ---------------- Threefry-2x32 (20 rounds), JAX-compatible ----------------
__device__ __forceinline__ void tf2x32_dev(uint32_t k0, uint32_t k1,
                                           uint32_t x0, uint32_t x1,
                                           uint32_t& o0, uint32_t& o1) {
  uint32_t ks2 = k0 ^ k1 ^ 0x1BD11BDAu;
  x0 += k0; x1 += k1;
#define TF_RND(r) { x0 += x1; x1 = (x1 << r) | (x1 >> (32 - r)); x1 ^= x0; }
  TF_RND(13) TF_RND(15) TF_RND(26) TF_RND(6)
  x0 += k1;  x1 += ks2 + 1u;
  TF_RND(17) TF_RND(29) TF_RND(16) TF_RND(24)
  x0 += ks2; x1 += k0 + 2u;
  TF_RND(13) TF_RND(15) TF_RND(26) TF_RND(6)
  x0 += k0;  x1 += k1 + 3u;
  TF_RND(17) TF_RND(29) TF_RND(16) TF_RND(24)
  x0 += k1;  x1 += ks2 + 4u;
  TF_RND(13) TF_RND(15) TF_RND(26) TF_RND(6)
  x0 += ks2; x1 += k0 + 5u;
#undef TF_RND
  o0 = x0; o1 = x1;
}

static inline uint32_t rotl32h(uint32_t x, int r) { return (x << r) | (x >> (32 - r)); }
static void tf2x32_host(uint32_t k0, uint32_t k1, uint32_t x0, uint32_t x1,
                        uint32_t* o0, uint32_t* o1) {
  uint32_t ks[3] = { k0, k1, k0 ^ k1 ^ 0x1BD11BDAu };
  static const int R[8] = {13, 15, 26, 6, 17, 29, 16, 24};
  x0 += k0; x1 += k1;
  for (int g = 0; g < 5; ++g) {
    const int* rr = (g & 1) ? (R + 4) : R;
    for (int i = 0; i < 4; ++i) { x0 += x1; x1 = rotl32h(x1, rr[i]); x1 ^= x0; }
    x0 += ks[(g + 1) % 3];
    x1 += ks[(g + 2) % 3] + (uint32_t)(g + 1);
  }
  *o0 = x0; *o1 = x1;
}

// ---------------- K1: label bitmasks ----------------
__global__ void k_labels(const float* __restrict__ gt, uint32_t* __restrict__ lbits) {
  int i = blockIdx.x * blockDim.x + threadIdx.x;
  if (i >= NB) return;
  uint32_t m = 0u;
#pragma unroll
  for (int c = 0; c < NC; ++c)
    if (gt[i * NC + c] != 0.0f) m |= (1u << c);
  lbits[i] = m;
}

// ---------------- K2: row norms ----------------
__global__ void k_norm(const float* __restrict__ pred, float* __restrict__ norm) {
  int row = blockIdx.x;
  const float4* p = (const float4*)(pred + (size_t)row * ND);
  float4 v = p[threadIdx.x];
  float s = v.x * v.x + v.y * v.y + v.z * v.z + v.w * v.w;
#pragma unroll
  for (int o = 32; o > 0; o >>= 1) s += __shfl_down(s, o, 64);
  __shared__ float red[4];
  int wave = threadIdx.x >> 6, lane = threadIdx.x & 63;
  if (lane == 0) red[wave] = s;
  __syncthreads();
  if (threadIdx.x == 0) norm[row] = sqrtf(red[0] + red[1] + red[2] + red[3]);
}

// ---------------- K3: gumbel-argmax sampling (the heavy kernel) ----------------
__global__ void __launch_bounds__(256) k_sample(
    const uint32_t* __restrict__ lbits,
    uint32_t kp0, uint32_t kp1, uint32_t kn0, uint32_t kn1,
    int* __restrict__ pos_idx, int* __restrict__ neg_idx) {
  __shared__ uint32_t lb[NB];            // 32 KiB label table
  __shared__ long long rp[256], rn[256]; // reduction buffers
  for (int t = threadIdx.x; t < NB; t += 256) lb[t] = lbits[t];
  __syncthreads();

  const int i = blockIdx.x;
  const uint32_t bi = lb[i];
  const bool has = (bi != 0u);
  const uint32_t fbase = (uint32_t)i * (uint32_t)NB; // < 2^26, hi word of counter = 0

  long long bestP = -1, bestN = -1;
#pragma unroll 4
  for (int k = 0; k < 32; ++k) {
    const int j = (k << 8) + (int)threadIdx.x;
    const uint32_t bj = lb[j];
    // exactly one of {pos,neg} is true for every j -> one threefry per element
    const bool isPos = has ? ((bi & bj) != 0u) : (bj == 0u);
    const uint32_t K0 = isPos ? kp0 : kn0;
    const uint32_t K1 = isPos ? kp1 : kn1;
    uint32_t w0, w1;
    tf2x32_dev(K0, K1, 0u, fbase + (uint32_t)j, w0, w1);
    const uint32_t ukey = (w0 ^ w1) >> 9; // monotone key for gumbel argmax
    const long long cand = ((long long)ukey << 13) | (long long)(8191 - j);
    if (isPos) { if (cand > bestP) bestP = cand; }
    else       { if (cand > bestN) bestN = cand; }
  }

  rp[threadIdx.x] = bestP; rn[threadIdx.x] = bestN;
  __syncthreads();
#pragma unroll
  for (int s = 128; s > 0; s >>= 1) {
    if ((int)threadIdx.x < s) {
      if (rp[threadIdx.x + s] > rp[threadIdx.x]) rp[threadIdx.x] = rp[threadIdx.x + s];
      if (rn[threadIdx.x + s] > rn[threadIdx.x]) rn[threadIdx.x] = rn[threadIdx.x + s];
    }
    __syncthreads();
  }
  if (threadIdx.x == 0) {
    long long bp = rp[0], bn = rn[0];
    pos_idx[i] = (bp < 0) ? 0 : (8191 - (int)(bp & 8191));
    neg_idx[i] = (bn < 0) ? 0 : (8191 - (int)(bn & 8191));
  }
}

// ---------------- K4: per-row triplet cosine loss ----------------
__global__ void k_loss(const float* __restrict__ pred, const float* __restrict__ norm,
                       const int* __restrict__ pos_idx, const int* __restrict__ neg_idx,
                       float* __restrict__ losses) {
  const int i = blockIdx.x;
  const int p = pos_idx[i];
  const int n = neg_idx[i];
  const float4* A = (const float4*)(pred + (size_t)i * ND);
  const float4* P = (const float4*)(pred + (size_t)p * ND);
  const float4* Nn = (const float4*)(pred + (size_t)n * ND);
  float4 a = A[threadIdx.x], pp = P[threadIdx.x], nn = Nn[threadIdx.x];
  float dp = a.x * pp.x + a.y * pp.y + a.z * pp.z + a.w * pp.w;
  float dn = a.x * nn.x + a.y * nn.y + a.z * nn.z + a.w * nn.w;
#pragma unroll
  for (int o = 32; o > 0; o >>= 1) {
    dp += __shfl_down(dp, o, 64);
    dn += __shfl_down(dn, o, 64);
  }
  __shared__ float rdp[4], rdn[4];
  int wave = threadIdx.x >> 6, lane = threadIdx.x & 63;
  if (lane == 0) { rdp[wave] = dp; rdn[wave] = dn; }
  __syncthreads();
  if (threadIdx.x == 0) {
    float DP = rdp[0] + rdp[1] + rdp[2] + rdp[3];
    float DN = rdn[0] + rdn[1] + rdn[2] + rdn[3];
    float na = norm[i];
    float cp = DP / fmaxf(na * norm[p], 1e-6f);
    float cn = DN / fmaxf(na * norm[n], 1e-6f);
    losses[i] = fmaxf(cp - cn + 0.1f, 0.0f);
  }
}

// ---------------- K5: mean ----------------
__global__ void k_mean(const float* __restrict__ losses, float* __restrict__ out) {
  float s = 0.0f;
  for (int k = threadIdx.x; k < NB; k += 256) s += losses[k];
#pragma unroll
  for (int o = 32; o > 0; o >>= 1) s += __shfl_down(s, o, 64);
  __shared__ float red[4];
  int wave = threadIdx.x >> 6, lane = threadIdx.x & 63;
  if (lane == 0) red[wave] = s;
  __syncthreads();
  if (threadIdx.x == 0) out[0] = (red[0] + red[1] + red[2] + red[3]) / (float)NB;
}

extern "C" void kernel_launch(void* const* d_in, const int* in_sizes, int n_in,
                              void* d_out, int out_size, void* d_ws, size_t ws_size,
                              hipStream_t stream) {
  const float* pred = (const float*)d_in[0]; // [8192,1024] f32
  const float* gt   = (const float*)d_in[1]; // [8192,14]  f32
  float* out = (float*)d_out;

  char* ws = (char*)d_ws;
  uint32_t* lbits = (uint32_t*)(ws);            // 32 KiB
  float*    norms = (float*)(ws + 32768);       // 32 KiB
  int*      posi  = (int*)(ws + 65536);         // 32 KiB
  int*      negi  = (int*)(ws + 98304);         // 32 KiB
  float*    losses= (float*)(ws + 131072);      // 32 KiB

  // JAX partitionable semantics: key(42) = (0,42);
  // split -> foldlike: kp = T(key,(0,0)), kn = T(key,(0,1))  (full output pair each)
  uint32_t kp0, kp1, kn0, kn1;
  tf2x32_host(0u, 42u, 0u, 0u, &kp0, &kp1);
  tf2x32_host(0u, 42u, 0u, 1u, &kn0, &kn1);

  k_labels<<<(NB + 255) / 256, 256, 0, stream>>>(gt, lbits);
  k_norm<<<NB, 256, 0, stream>>>(pred, norms);
  k_sample<<<NB, 256, 0, stream>>>(lbits, kp0, kp1, kn0, kn1, posi, negi);
  k_loss<<<NB, 256, 0, stream>>>(pred, norms, posi, negi, losses);
  k_mean<<<1, 256, 0, stream>>>(losses, out);
}

// Round 2
// 241.782 us; speedup vs baseline: 1.4422x; 1.4422x over previous
//
#include <hip/hip_runtime.h>
#include <hip/hip_bf16.h>
#include <stdint.h>

#define NB 8192
#define ND 1024
#define NC 14

// ---------------- host Threefry-2x32 (20 rounds), JAX-compatible ----------------
static inline uint32_t rotl32h(uint32_t x, int r) { return (x << r) | (x >> (32 - r)); }
static void tf2x32_host(uint32_t k0, uint32_t k1, uint32_t x0, uint32_t x1,
                        uint32_t* o0, uint32_t* o1) {
  uint32_t ks[3] = { k0, k1, k0 ^ k1 ^ 0x1BD11BDAu };
  static const int R[8] = {13, 15, 26, 6, 17, 29, 16, 24};
  x0 += k0; x1 += k1;
  for (int g = 0; g < 5; ++g) {
    const int* rr = (g & 1) ? (R + 4) : R;
    for (int i = 0; i < 4; ++i) { x0 += x1; x1 = rotl32h(x1, rr[i]); x1 ^= x0; }
    x0 += ks[(g + 1) % 3];
    x1 += ks[(g + 2) % 3] + (uint32_t)(g + 1);
  }
  *o0 = x0; *o1 = x1;
}

// ---------------- K1: row norms + label bitmasks (fused) ----------------
__global__ void k_norm(const float* __restrict__ pred, const float* __restrict__ gt,
                       float* __restrict__ norm, uint32_t* __restrict__ lbits) {
  const int row = blockIdx.x;
  const float4* p = (const float4*)(pred + (size_t)row * ND);
  float4 v = p[threadIdx.x];
  float s = v.x * v.x + v.y * v.y + v.z * v.z + v.w * v.w;
#pragma unroll
  for (int o = 32; o > 0; o >>= 1) s += __shfl_down(s, o, 64);
  __shared__ float red[4];
  const int wave = threadIdx.x >> 6, lane = threadIdx.x & 63;
  if (lane == 0) red[wave] = s;
  // label bitmask via ballot over first 14 lanes of wave 0
  unsigned long long b =
      __ballot((int)threadIdx.x < NC && gt[row * NC + (int)threadIdx.x] != 0.0f);
  __syncthreads();
  if (threadIdx.x == 0) {
    lbits[row] = (uint32_t)(b & 0x3FFFull);
    norm[row] = sqrtf(red[0] + red[1] + red[2] + red[3]);
  }
}

// ---------------- K2: gumbel-argmax sampling (the heavy kernel) ----------------
template <bool HAS>
__device__ __forceinline__ void sample_loop(
    const uint32_t* __restrict__ lbits, uint32_t bi, uint32_t fbase, uint32_t tid,
    uint32_t kp0, uint32_t kp1, uint32_t kps2,
    uint32_t kn0, uint32_t kn1, uint32_t kns2,
    uint32_t& bkP, uint32_t& bjP, uint32_t& bkN, uint32_t& bjN) {
#pragma unroll 8
  for (uint32_t k = 0; k < 32; ++k) {
    const uint32_t j = (k << 8) + tid;
    const uint32_t bj = lbits[j];
    const bool isPos = HAS ? ((bi & bj) != 0u) : (bj == 0u);
    const uint32_t K0 = isPos ? kp0 : kn0;
    const uint32_t K1 = isPos ? kp1 : kn1;
    const uint32_t KS2 = isPos ? kps2 : kns2;
    uint32_t x0 = K0;
    uint32_t x1 = fbase + j + K1;
#define TFR(r) { x0 += x1; x1 = (x1 << r) | (x1 >> (32 - r)); x1 ^= x0; }
    TFR(13) TFR(15) TFR(26) TFR(6)
    x0 += K1;  x1 += KS2 + 1u;
    TFR(17) TFR(29) TFR(16) TFR(24)
    x0 += KS2; x1 += K0 + 2u;
    TFR(13) TFR(15) TFR(26) TFR(6)
    x0 += K0;  x1 += K1 + 3u;
    TFR(17) TFR(29) TFR(16) TFR(24)
    x0 += K1;  x1 += KS2 + 4u;
    TFR(13) TFR(15) TFR(26) TFR(6)
    x0 += KS2; x1 += K0 + 5u;
#undef TFR
    // key+1 so that a real candidate always beats the 0-init; strict > keeps
    // the first (smallest-j) occurrence within a thread, matching jnp.argmax.
    const uint32_t key1 = ((x0 ^ x1) >> 9) + 1u;
    const bool gtP = isPos && (key1 > bkP);
    bkP = gtP ? key1 : bkP;
    bjP = gtP ? j : bjP;
    const bool gtN = (!isPos) && (key1 > bkN);
    bkN = gtN ? key1 : bkN;
    bjN = gtN ? j : bjN;
  }
}

__global__ void __launch_bounds__(256) k_sample(
    const uint32_t* __restrict__ lbits,
    uint32_t kp0, uint32_t kp1, uint32_t kps2,
    uint32_t kn0, uint32_t kn1, uint32_t kns2,
    int* __restrict__ pos_idx, int* __restrict__ neg_idx) {
  const int i = blockIdx.x;
  const uint32_t bi = lbits[i];
  const uint32_t fbase = (uint32_t)i << 13;
  const uint32_t tid = threadIdx.x;

  uint32_t bkP = 0u, bjP = 0u, bkN = 0u, bjN = 0u;
  if (bi != 0u)  // wave-uniform (whole block = one row)
    sample_loop<true>(lbits, bi, fbase, tid, kp0, kp1, kps2, kn0, kn1, kns2,
                      bkP, bjP, bkN, bjN);
  else
    sample_loop<false>(lbits, bi, fbase, tid, kp0, kp1, kps2, kn0, kn1, kns2,
                       bkP, bjP, bkN, bjN);

  // wave-level reduction with explicit (key, smaller-j) tie-break
#pragma unroll
  for (int off = 32; off > 0; off >>= 1) {
    uint32_t k2 = __shfl_down(bkP, off, 64), j2 = __shfl_down(bjP, off, 64);
    if (k2 > bkP || (k2 == bkP && j2 < bjP)) { bkP = k2; bjP = j2; }
    k2 = __shfl_down(bkN, off, 64); j2 = __shfl_down(bjN, off, 64);
    if (k2 > bkN || (k2 == bkN && j2 < bjN)) { bkN = k2; bjN = j2; }
  }
  __shared__ uint32_t sk[2][4], sj[2][4];
  const int wave = (int)tid >> 6, lane = (int)tid & 63;
  if (lane == 0) { sk[0][wave] = bkP; sj[0][wave] = bjP; sk[1][wave] = bkN; sj[1][wave] = bjN; }
  __syncthreads();
  if (tid == 0) {
    uint32_t bk = sk[0][0], bj = sj[0][0];
#pragma unroll
    for (int w = 1; w < 4; ++w)
      if (sk[0][w] > bk || (sk[0][w] == bk && sj[0][w] < bj)) { bk = sk[0][w]; bj = sj[0][w]; }
    pos_idx[i] = (bk == 0u) ? 0 : (int)bj;
    bk = sk[1][0]; bj = sj[1][0];
#pragma unroll
    for (int w = 1; w < 4; ++w)
      if (sk[1][w] > bk || (sk[1][w] == bk && sj[1][w] < bj)) { bk = sk[1][w]; bj = sj[1][w]; }
    neg_idx[i] = (bk == 0u) ? 0 : (int)bj;
  }
}

// ---------------- K3: per-row triplet cosine loss ----------------
__global__ void k_loss(const float* __restrict__ pred, const float* __restrict__ norm,
                       const int* __restrict__ pos_idx, const int* __restrict__ neg_idx,
                       float* __restrict__ losses) {
  const int i = blockIdx.x;
  const int p = pos_idx[i];
  const int n = neg_idx[i];
  const float4* A = (const float4*)(pred + (size_t)i * ND);
  const float4* P = (const float4*)(pred + (size_t)p * ND);
  const float4* Nn = (const float4*)(pred + (size_t)n * ND);
  float4 a = A[threadIdx.x], pp = P[threadIdx.x], nn = Nn[threadIdx.x];
  float dp = a.x * pp.x + a.y * pp.y + a.z * pp.z + a.w * pp.w;
  float dn = a.x * nn.x + a.y * nn.y + a.z * nn.z + a.w * nn.w;
#pragma unroll
  for (int o = 32; o > 0; o >>= 1) {
    dp += __shfl_down(dp, o, 64);
    dn += __shfl_down(dn, o, 64);
  }
  __shared__ float rdp[4], rdn[4];
  int wave = threadIdx.x >> 6, lane = threadIdx.x & 63;
  if (lane == 0) { rdp[wave] = dp; rdn[wave] = dn; }
  __syncthreads();
  if (threadIdx.x == 0) {
    float DP = rdp[0] + rdp[1] + rdp[2] + rdp[3];
    float DN = rdn[0] + rdn[1] + rdn[2] + rdn[3];
    float na = norm[i];
    float cp = DP / fmaxf(na * norm[p], 1e-6f);
    float cn = DN / fmaxf(na * norm[n], 1e-6f);
    losses[i] = fmaxf(cp - cn + 0.1f, 0.0f);
  }
}

// ---------------- K4: mean ----------------
__global__ void k_mean(const float* __restrict__ losses, float* __restrict__ out) {
  float s = 0.0f;
  for (int k = threadIdx.x; k < NB; k += 256) s += losses[k];
#pragma unroll
  for (int o = 32; o > 0; o >>= 1) s += __shfl_down(s, o, 64);
  __shared__ float red[4];
  int wave = threadIdx.x >> 6, lane = threadIdx.x & 63;
  if (lane == 0) red[wave] = s;
  __syncthreads();
  if (threadIdx.x == 0) out[0] = (red[0] + red[1] + red[2] + red[3]) / (float)NB;
}

extern "C" void kernel_launch(void* const* d_in, const int* in_sizes, int n_in,
                              void* d_out, int out_size, void* d_ws, size_t ws_size,
                              hipStream_t stream) {
  const float* pred = (const float*)d_in[0]; // [8192,1024] f32
  const float* gt   = (const float*)d_in[1]; // [8192,14]  f32
  float* out = (float*)d_out;

  char* ws = (char*)d_ws;
  uint32_t* lbits = (uint32_t*)(ws);            // 32 KiB
  float*    norms = (float*)(ws + 32768);       // 32 KiB
  int*      posi  = (int*)(ws + 65536);         // 32 KiB
  int*      negi  = (int*)(ws + 98304);         // 32 KiB
  float*    losses= (float*)(ws + 131072);      // 32 KiB

  // JAX partitionable-threefry: key(42) = (0,42); split -> kp=T(key,(0,0)), kn=T(key,(0,1))
  uint32_t kp0, kp1, kn0, kn1;
  tf2x32_host(0u, 42u, 0u, 0u, &kp0, &kp1);
  tf2x32_host(0u, 42u, 0u, 1u, &kn0, &kn1);
  const uint32_t kps2 = kp0 ^ kp1 ^ 0x1BD11BDAu;
  const uint32_t kns2 = kn0 ^ kn1 ^ 0x1BD11BDAu;

  k_norm<<<NB, 256, 0, stream>>>(pred, gt, norms, lbits);
  k_sample<<<NB, 256, 0, stream>>>(lbits, kp0, kp1, kps2, kn0, kn1, kns2, posi, negi);
  k_loss<<<NB, 256, 0, stream>>>(pred, norms, posi, negi, losses);
  k_mean<<<1, 256, 0, stream>>>(losses, out);
}